// Round 7
// baseline (751.277 us; speedup 1.0000x reference)
//
#include <hip/hip_runtime.h>
#include <cstdint>
#include <cstddef>

#define HIDDEN 128
#define N_NODES_C 50000
#define NBKT 196          // ceil(50000/256) buckets of 256 nodes
#define EPB 4096          // edges per partition block
#define STG 6144          // LDS stage ints in bucket_sort (max bucket ~4350)

typedef short bf16x8 __attribute__((ext_vector_type(8)));
typedef unsigned short u16x8 __attribute__((ext_vector_type(8)));
typedef float f32x4 __attribute__((ext_vector_type(4)));

__device__ inline unsigned short f2b(float x) {   // fp32 -> bf16 RNE
    union { float f; unsigned int u; } v; v.f = x;
    unsigned int r = v.u + 0x7FFFu + ((v.u >> 16) & 1u);
    return (unsigned short)(r >> 16);
}
__device__ inline float b2f(unsigned short h) {
    union { unsigned int u; float f; } v; v.u = ((unsigned int)h) << 16;
    return v.f;
}

// ---- prep: bf16 transposed weights + zero bucket counters ----
__global__ __launch_bounds__(256) void prep_kernel(
    const float* __restrict__ enc_w, const float* __restrict__ p1a_w,
    const float* __restrict__ lin1_w, const float* __restrict__ p2a_w,
    const float* __restrict__ lin2_w,
    unsigned short* __restrict__ encT,
    unsigned short* __restrict__ A1T, unsigned short* __restrict__ B1T,
    unsigned short* __restrict__ L1T,
    unsigned short* __restrict__ A2T, unsigned short* __restrict__ B2T,
    unsigned short* __restrict__ L2T,
    int* __restrict__ bcount)
{
    const int b = blockIdx.x, t = threadIdx.x;
    if (b < 16) {            // encT [128][256] from enc_w [256][128]
        for (int i = t; i < 8 * 256; i += 256) {
            int n = b * 8 + (i >> 8);
            int k = i & 255;
            encT[n * 256 + k] = f2b(enc_w[k * 128 + n]);
        }
    } else if (b < 64) {     // six [128][128] transposes, 16 rows/block
        const int mi  = (b - 16) >> 3;
        const int sub = (b - 16) & 7;
        const float* src; unsigned short* dst;
        switch (mi) {
            case 0: src = p1a_w;              dst = A1T; break;
            case 1: src = p1a_w + 128 * 128;  dst = B1T; break;
            case 2: src = lin1_w;             dst = L1T; break;
            case 3: src = p2a_w;              dst = A2T; break;
            case 4: src = p2a_w + 128 * 128;  dst = B2T; break;
            default: src = lin2_w;            dst = L2T; break;
        }
        for (int i = t; i < 16 * 128; i += 256) {
            int n = sub * 16 + (i >> 7);
            int k = i & 127;
            dst[n * 128 + k] = f2b(src[k * 128 + n]);
        }
    } else {                 // zero bucket counters
        if (t < NBKT) bcount[t] = 0;
    }
}

// ---- CSR build: bucketed counting sort ----
__global__ __launch_bounds__(256) void bucket_hist(
    const int* __restrict__ ei, int E, int* __restrict__ bcount)
{
    const int base = (blockIdx.x * 256 + threadIdx.x) * 4;
    if (base >= E) return;
    const int* dstp = ei + E;
    if (base + 3 < E) {
        int4 d = *(const int4*)(dstp + base);
        atomicAdd(&bcount[d.x >> 8], 1);
        atomicAdd(&bcount[d.y >> 8], 1);
        atomicAdd(&bcount[d.z >> 8], 1);
        atomicAdd(&bcount[d.w >> 8], 1);
    } else {
        for (int j = 0; j < 4 && base + j < E; ++j)
            atomicAdd(&bcount[dstp[base + j] >> 8], 1);
    }
}

__global__ __launch_bounds__(256) void bucket_scan(
    const int* __restrict__ bcount, int* __restrict__ bOffs,
    int* __restrict__ cursor)
{
    __shared__ int part[256];
    const int t = threadIdx.x;
    const int v = (t < NBKT) ? bcount[t] : 0;
    part[t] = v;
    __syncthreads();
    for (int off = 1; off < 256; off <<= 1) {
        int u = (t >= off) ? part[t - off] : 0;
        __syncthreads();
        part[t] += u;
        __syncthreads();
    }
    const int incl = part[t];
    const int excl = incl - v;
    if (t < NBKT) { bOffs[t] = excl; cursor[t] = excl; }
    if (t == NBKT - 1) bOffs[NBKT] = incl;
}

// partition edges into bucket-contiguous ebuf with LDS staging (coalesced runs)
__global__ __launch_bounds__(256) void partition_kernel(
    const int* __restrict__ ei, int E, int* __restrict__ cursor,
    int2* __restrict__ ebuf)
{
    __shared__ int cnt[256], lofs[256], gbase[256], lcur[256];
    __shared__ int2 stage[EPB];
    __shared__ int tgt[EPB];
    const int t = threadIdx.x;
    const int base = blockIdx.x * EPB;
    const int n = min(EPB, E - base);

    int msrc[EPB / 256], mdst[EPB / 256];
    #pragma unroll
    for (int j = 0; j < EPB / 256; ++j) {
        const int idx = j * 256 + t;
        if (idx < n) { msrc[j] = ei[base + idx]; mdst[j] = ei[E + base + idx]; }
        else mdst[j] = -1;
    }
    cnt[t] = 0;
    __syncthreads();
    #pragma unroll
    for (int j = 0; j < EPB / 256; ++j)
        if (mdst[j] >= 0) atomicAdd(&cnt[mdst[j] >> 8], 1);
    __syncthreads();
    const int cv = cnt[t];
    lofs[t] = cv;
    __syncthreads();
    for (int off = 1; off < 256; off <<= 1) {
        int u = (t >= off) ? lofs[t - off] : 0;
        __syncthreads();
        lofs[t] += u;
        __syncthreads();
    }
    const int excl = lofs[t] - cv;
    gbase[t] = (cv > 0) ? atomicAdd(&cursor[t], cv) : 0;
    lcur[t] = 0;
    __syncthreads();
    lofs[t] = excl;
    __syncthreads();
    #pragma unroll
    for (int j = 0; j < EPB / 256; ++j) {
        if (mdst[j] >= 0) {
            const int b = mdst[j] >> 8;
            const int lp = atomicAdd(&lcur[b], 1);
            const int slot = lofs[b] + lp;
            stage[slot] = make_int2(msrc[j], mdst[j]);
            tgt[slot] = gbase[b] + lp;
        }
    }
    __syncthreads();
    for (int i = t; i < n; i += 256)
        ebuf[tgt[i]] = stage[i];
}

// per-bucket exact counting sort -> srcs (coalesced) + CSR offs
__global__ __launch_bounds__(256) void bucket_sort(
    const int2* __restrict__ ebuf, const int* __restrict__ bOffs,
    int* __restrict__ srcs, int* __restrict__ offs, int M)
{
    __shared__ int cnt[256], lofs[256], lcur[256];
    __shared__ int stage[STG];
    const int b = blockIdx.x, t = threadIdx.x;
    const int n0 = b << 8;
    const int lo = bOffs[b], hi = bOffs[b + 1];

    cnt[t] = 0;
    __syncthreads();
    for (int i = lo + t; i < hi; i += 256)
        atomicAdd(&cnt[ebuf[i].y - n0], 1);
    __syncthreads();
    const int cv = cnt[t];
    lofs[t] = cv;
    __syncthreads();
    for (int off = 1; off < 256; off <<= 1) {
        int u = (t >= off) ? lofs[t - off] : 0;
        __syncthreads();
        lofs[t] += u;
        __syncthreads();
    }
    const int excl = lofs[t] - cv;
    const int nn = min(256, M - n0);
    if (t < nn) offs[n0 + t] = lo + excl;
    if (b == NBKT - 1 && t == 0) offs[M] = hi;
    lcur[t] = 0;
    __syncthreads();
    lofs[t] = excl;
    __syncthreads();
    for (int i = lo + t; i < hi; i += 256) {
        const int2 p = ebuf[i];
        const int d = p.y - n0;
        const int lp = atomicAdd(&lcur[d], 1);
        const int slot = lofs[d] + lp;
        if (slot < STG) stage[slot] = p.x;
        else srcs[lo + slot] = p.x;       // overflow fallback (same target)
    }
    __syncthreads();
    const int n = hi - lo;
    for (int i = t; i < n && i < STG; i += 256)
        srcs[lo + i] = stage[i];
}

// ---- encoder: h0 = relu(x @ enc_w + enc_b), bf16 out. MFMA 16x16x32. ----
__global__ __launch_bounds__(256) void enc_mfma(
    const float* __restrict__ x, const unsigned short* __restrict__ encT,
    const float* __restrict__ enc_b, unsigned short* __restrict__ h0, int M)
{
    const int wave = threadIdx.x >> 6, lane = threadIdx.x & 63;
    const int rowBase = blockIdx.x * 64 + wave * 16;
    const int sl = lane & 15, kg = lane >> 4;
    const int row_a = rowBase + sl;

    f32x4 acc[8] = {};
    for (int ks = 0; ks < 8; ++ks) {
        const int k0 = ks * 32 + kg * 8;
        bf16x8 a = {};
        if (row_a < M) {
            const float* xp = x + (size_t)row_a * 256 + k0;
            float4 f0 = *(const float4*)xp;
            float4 f1 = *(const float4*)(xp + 4);
            a[0] = (short)f2b(f0.x); a[1] = (short)f2b(f0.y);
            a[2] = (short)f2b(f0.z); a[3] = (short)f2b(f0.w);
            a[4] = (short)f2b(f1.x); a[5] = (short)f2b(f1.y);
            a[6] = (short)f2b(f1.z); a[7] = (short)f2b(f1.w);
        }
        #pragma unroll
        for (int ct = 0; ct < 8; ++ct) {
            bf16x8 bfr = *(const bf16x8*)(encT + (size_t)(ct * 16 + sl) * 256 + k0);
            acc[ct] = __builtin_amdgcn_mfma_f32_16x16x32_bf16(a, bfr, acc[ct], 0, 0, 0);
        }
    }
    #pragma unroll
    for (int ct = 0; ct < 8; ++ct) {
        const int col = ct * 16 + sl;
        const float eb = enc_b[col];
        #pragma unroll
        for (int r = 0; r < 4; ++r) {
            const int row = rowBase + kg * 4 + r;
            if (row < M)
                h0[(size_t)row * 128 + col] = f2b(fmaxf(acc[ct][r] + eb, 0.f));
        }
    }
}

// ---- fused per-layer precompute: A -> outA [M][128]; B,L -> outBL [M][256] ----
__global__ __launch_bounds__(256) void fused3_mfma(
    const unsigned short* __restrict__ h,
    const unsigned short* __restrict__ AT, const unsigned short* __restrict__ BT,
    const unsigned short* __restrict__ LT, const float* __restrict__ linb,
    unsigned short* __restrict__ outA, unsigned short* __restrict__ outBL,
    int M)
{
    const int wave = threadIdx.x >> 6, lane = threadIdx.x & 63;
    const int rowBase = blockIdx.x * 64 + wave * 16;
    const int sl = lane & 15, kg = lane >> 4;
    const int row_a = rowBase + sl;

    bf16x8 afr[4];
    #pragma unroll
    for (int ks = 0; ks < 4; ++ks) {
        if (row_a < M)
            afr[ks] = *(const bf16x8*)(h + (size_t)row_a * 128 + ks * 32 + kg * 8);
        else
            afr[ks] = bf16x8{};
    }

    #pragma unroll
    for (int m = 0; m < 3; ++m) {
        const unsigned short* WT = (m == 0) ? AT : (m == 1) ? BT : LT;
        unsigned short* op  = (m == 0) ? outA : outBL;
        const int stride    = (m == 0) ? 128 : 256;
        const int coff      = (m == 2) ? 128 : 0;

        f32x4 acc[8] = {};
        #pragma unroll
        for (int ks = 0; ks < 4; ++ks) {
            const int k0 = ks * 32 + kg * 8;
            #pragma unroll
            for (int ct = 0; ct < 8; ++ct) {
                bf16x8 bfr = *(const bf16x8*)(WT + (size_t)(ct * 16 + sl) * 128 + k0);
                acc[ct] = __builtin_amdgcn_mfma_f32_16x16x32_bf16(afr[ks], bfr, acc[ct], 0, 0, 0);
            }
        }
        #pragma unroll
        for (int ct = 0; ct < 8; ++ct) {
            const int col = ct * 16 + sl;
            const float lb = (m == 2) ? linb[col] : 0.f;
            #pragma unroll
            for (int r = 0; r < 4; ++r) {
                const int row = rowBase + kg * 4 + r;
                if (row < M)
                    op[(size_t)row * stride + coff + col] = f2b(acc[ct][r] + lb);
            }
        }
    }
}

// ---- gather: one wave per dst node, one edge per 16-lane group.
// B and L interleaved in BL[M][256] (B at +0, L at +128).
template<bool CLS>
__global__ __launch_bounds__(256) void gather_bf16(
    const int* __restrict__ offs, const int* __restrict__ srcs,
    const unsigned short* __restrict__ Amat, const unsigned short* __restrict__ BL,
    const float* __restrict__ hid_b, const float* __restrict__ pw,
    const float* __restrict__ pb,
    unsigned short* __restrict__ outH,
    const float* __restrict__ cls_w, const float* __restrict__ cls_b,
    float* __restrict__ outC, int M)
{
    const int node = blockIdx.x * 4 + (threadIdx.x >> 6);
    if (node >= M) return;
    const int lane = threadIdx.x & 63;
    const int grp = lane >> 4;
    const int sl  = lane & 15;
    const int c8  = sl * 8;

    float a[8], w[8];
    {
        u16x8 av = *(const u16x8*)(Amat + (size_t)node * 128 + c8);
        float4 h0 = *(const float4*)(hid_b + c8);
        float4 h1 = *(const float4*)(hid_b + c8 + 4);
        a[0] = b2f(av[0]) + h0.x; a[1] = b2f(av[1]) + h0.y;
        a[2] = b2f(av[2]) + h0.z; a[3] = b2f(av[3]) + h0.w;
        a[4] = b2f(av[4]) + h1.x; a[5] = b2f(av[5]) + h1.y;
        a[6] = b2f(av[6]) + h1.z; a[7] = b2f(av[7]) + h1.w;
        float4 p0 = *(const float4*)(pw + c8);
        float4 p1 = *(const float4*)(pw + c8 + 4);
        w[0] = p0.x; w[1] = p0.y; w[2] = p0.z; w[3] = p0.w;
        w[4] = p1.x; w[5] = p1.y; w[6] = p1.z; w[7] = p1.w;
    }
    const float pb0 = pb[0];
    float acc[8] = {};

    const int start = offs[node], end = offs[node + 1];
    for (int idx = start + grp; idx < end; idx += 4) {
        const int s = srcs[idx];
        const unsigned short* row = BL + (size_t)s * 256 + c8;
        u16x8 bv = *(const u16x8*)row;
        u16x8 lv = *(const u16x8*)(row + 128);

        float part = 0.f;
        #pragma unroll
        for (int j = 0; j < 8; ++j)
            part += fmaxf(a[j] + b2f(bv[j]), 0.f) * w[j];
        part += __shfl_xor(part, 8);
        part += __shfl_xor(part, 4);
        part += __shfl_xor(part, 2);
        part += __shfl_xor(part, 1);

        const float pick = 1.f / (1.f + __expf(-(part + pb0)));
        #pragma unroll
        for (int j = 0; j < 8; ++j)
            acc[j] = fmaf(pick, b2f(lv[j]), acc[j]);
    }

    #pragma unroll
    for (int j = 0; j < 8; ++j) acc[j] += __shfl_xor(acc[j], 16);
    #pragma unroll
    for (int j = 0; j < 8; ++j) acc[j] += __shfl_xor(acc[j], 32);

    if (CLS) {
        float p0 = 0.f, p1 = 0.f;
        #pragma unroll
        for (int j = 0; j < 8; ++j) {
            p0 = fmaf(acc[j], cls_w[(c8 + j) * 2 + 0], p0);
            p1 = fmaf(acc[j], cls_w[(c8 + j) * 2 + 1], p1);
        }
        #pragma unroll
        for (int off = 8; off > 0; off >>= 1) {
            p0 += __shfl_xor(p0, off);
            p1 += __shfl_xor(p1, off);
        }
        if (lane == 0) {
            outC[(size_t)node * 2 + 0] = p0 + cls_b[0];
            outC[(size_t)node * 2 + 1] = p1 + cls_b[1];
        }
    } else {
        if (grp == 0) {
            u16x8 o;
            #pragma unroll
            for (int j = 0; j < 8; ++j)
                o[j] = f2b(fmaxf(acc[j], 0.f));     // relu before layer 2
            *(u16x8*)(outH + (size_t)node * 128 + c8) = o;
        }
    }
}

extern "C" void kernel_launch(void* const* d_in, const int* in_sizes, int n_in,
                              void* d_out, int out_size, void* d_ws, size_t ws_size,
                              hipStream_t stream)
{
    const float* x      = (const float*)d_in[0];
    const int*   ei     = (const int*)d_in[1];
    const float* enc_w  = (const float*)d_in[2];
    const float* enc_b  = (const float*)d_in[3];
    const float* lin1_w = (const float*)d_in[4];
    const float* lin1_b = (const float*)d_in[5];
    const float* p1a_w  = (const float*)d_in[6];
    const float* p1a_b  = (const float*)d_in[7];
    const float* p1b_w  = (const float*)d_in[8];
    const float* p1b_b  = (const float*)d_in[9];
    const float* lin2_w = (const float*)d_in[10];
    const float* lin2_b = (const float*)d_in[11];
    const float* p2a_w  = (const float*)d_in[12];
    const float* p2a_b  = (const float*)d_in[13];
    const float* p2b_w  = (const float*)d_in[14];
    const float* p2b_b  = (const float*)d_in[15];
    const float* cls_w  = (const float*)d_in[16];
    const float* cls_b  = (const float*)d_in[17];

    const int M = N_NODES_C;
    const int E = in_sizes[1] / 2;
    const size_t HS = (size_t)M * HIDDEN;          // ushorts per [M][128]

    unsigned short* Hb0 = (unsigned short*)d_ws;   // h0 -> A2
    unsigned short* HA  = Hb0 + HS;                // A1 -> relu(h1)
    unsigned short* HBL = HA + HS;                 // [M][256] B|L interleaved
    unsigned short* encT = HBL + 2 * HS;
    unsigned short* A1T = encT + 128 * 256;
    unsigned short* B1T = A1T + 128 * 128;
    unsigned short* L1T = B1T + 128 * 128;
    unsigned short* A2T = L1T + 128 * 128;
    unsigned short* B2T = A2T + 128 * 128;
    unsigned short* L2T = B2T + 128 * 128;
    int* offs   = (int*)(L2T + 128 * 128);         // M+1
    int* srcs   = offs + M + 1;                    // E
    int* bcount = srcs + E;                        // NBKT
    int* cursor = bcount + NBKT;                   // NBKT
    int* bOffs  = cursor + NBKT;                   // NBKT+1
    int2* ebuf  = (int2*)HBL;                      // overlay: dead before HBL write

    const int ggrid = (M + 63) / 64;
    const int ngrid = (M + 3) / 4;
    const int hgrid = (E + 1023) / 1024;
    const int pgrid = (E + EPB - 1) / EPB;         // 196
    dim3 blk(256);

    // 1. weights bf16-transpose + zero bucket counters
    prep_kernel<<<65, blk, 0, stream>>>(enc_w, p1a_w, lin1_w, p2a_w, lin2_w,
                                        encT, A1T, B1T, L1T, A2T, B2T, L2T,
                                        bcount);
    // 2-5. CSR build via bucketed counting sort
    bucket_hist<<<hgrid, blk, 0, stream>>>(ei, E, bcount);
    bucket_scan<<<1, blk, 0, stream>>>(bcount, bOffs, cursor);
    partition_kernel<<<pgrid, blk, 0, stream>>>(ei, E, cursor, ebuf);
    bucket_sort<<<NBKT, blk, 0, stream>>>(ebuf, bOffs, srcs, offs, M);

    // 6. encoder
    enc_mfma<<<ggrid, blk, 0, stream>>>(x, encT, enc_b, Hb0, M);

    // 7-8. layer 1
    fused3_mfma<<<ggrid, blk, 0, stream>>>(Hb0, A1T, B1T, L1T, lin1_b,
                                           HA, HBL, M);
    gather_bf16<false><<<ngrid, blk, 0, stream>>>(offs, srcs, HA, HBL,
                                                  p1a_b, p1b_w, p1b_b,
                                                  HA, nullptr, nullptr, nullptr, M);

    // 9-10. layer 2 (+ fused classifier)
    fused3_mfma<<<ggrid, blk, 0, stream>>>(HA, A2T, B2T, L2T, lin2_b,
                                           Hb0, HBL, M);
    gather_bf16<true><<<ngrid, blk, 0, stream>>>(offs, srcs, Hb0, HBL,
                                                 p2a_b, p2b_w, p2b_b,
                                                 nullptr, cls_w, cls_b,
                                                 (float*)d_out, M);
}

// Round 8
// 310.798 us; speedup vs baseline: 2.4173x; 2.4173x over previous
//
#include <hip/hip_runtime.h>
#include <cstdint>
#include <cstddef>

#define HIDDEN 128
#define N_NODES_C 50000
#define NBKT 196          // ceil(50000/256) buckets of 256 nodes
#define EPB 4096          // edges per partition block
#define STG 6144          // LDS stage ints in bucket_sort (max bucket ~4350)

typedef short bf16x8 __attribute__((ext_vector_type(8)));
typedef unsigned short u16x8 __attribute__((ext_vector_type(8)));
typedef float f32x4 __attribute__((ext_vector_type(4)));

__device__ inline unsigned short f2b(float x) {   // fp32 -> bf16 RNE
    union { float f; unsigned int u; } v; v.f = x;
    unsigned int r = v.u + 0x7FFFu + ((v.u >> 16) & 1u);
    return (unsigned short)(r >> 16);
}
__device__ inline float b2f(unsigned short h) {
    union { unsigned int u; float f; } v; v.u = ((unsigned int)h) << 16;
    return v.f;
}

// ---- prep: bf16 transposed weights + zero bucket counters ----
__global__ __launch_bounds__(256) void prep_kernel(
    const float* __restrict__ enc_w, const float* __restrict__ p1a_w,
    const float* __restrict__ lin1_w, const float* __restrict__ p2a_w,
    const float* __restrict__ lin2_w,
    unsigned short* __restrict__ encT,
    unsigned short* __restrict__ A1T, unsigned short* __restrict__ B1T,
    unsigned short* __restrict__ L1T,
    unsigned short* __restrict__ A2T, unsigned short* __restrict__ B2T,
    unsigned short* __restrict__ L2T,
    int* __restrict__ bcount)
{
    const int b = blockIdx.x, t = threadIdx.x;
    if (b < 16) {            // encT [128][256] from enc_w [256][128]
        for (int i = t; i < 8 * 256; i += 256) {
            int n = b * 8 + (i >> 8);
            int k = i & 255;
            encT[n * 256 + k] = f2b(enc_w[k * 128 + n]);
        }
    } else if (b < 64) {     // six [128][128] transposes, 16 rows/block
        const int mi  = (b - 16) >> 3;
        const int sub = (b - 16) & 7;
        const float* src; unsigned short* dst;
        switch (mi) {
            case 0: src = p1a_w;              dst = A1T; break;
            case 1: src = p1a_w + 128 * 128;  dst = B1T; break;
            case 2: src = lin1_w;             dst = L1T; break;
            case 3: src = p2a_w;              dst = A2T; break;
            case 4: src = p2a_w + 128 * 128;  dst = B2T; break;
            default: src = lin2_w;            dst = L2T; break;
        }
        for (int i = t; i < 16 * 128; i += 256) {
            int n = sub * 16 + (i >> 7);
            int k = i & 127;
            dst[n * 128 + k] = f2b(src[k * 128 + n]);
        }
    } else {                 // zero bucket counters
        if (t < NBKT) bcount[t] = 0;
    }
}

// ---- CSR build: bucketed counting sort ----
// LDS-privatized histogram: one global atomic per (block,bucket), not per edge.
__global__ __launch_bounds__(256) void bucket_hist(
    const int* __restrict__ ei, int E, int* __restrict__ bcount)
{
    __shared__ int cnt[NBKT];
    const int t = threadIdx.x;
    if (t < NBKT) cnt[t] = 0;
    __syncthreads();

    const int base = blockIdx.x * EPB;
    const int n = min(EPB, E - base);
    const int* dstp = ei + E + base;
    for (int i = t * 4; i < n; i += 1024) {
        if (i + 3 < n) {
            int4 d = *(const int4*)(dstp + i);
            atomicAdd(&cnt[d.x >> 8], 1);
            atomicAdd(&cnt[d.y >> 8], 1);
            atomicAdd(&cnt[d.z >> 8], 1);
            atomicAdd(&cnt[d.w >> 8], 1);
        } else {
            for (int j = i; j < n; ++j) atomicAdd(&cnt[dstp[j] >> 8], 1);
        }
    }
    __syncthreads();
    if (t < NBKT && cnt[t] > 0) atomicAdd(&bcount[t], cnt[t]);
}

__global__ __launch_bounds__(256) void bucket_scan(
    const int* __restrict__ bcount, int* __restrict__ bOffs,
    int* __restrict__ cursor)
{
    __shared__ int part[256];
    const int t = threadIdx.x;
    const int v = (t < NBKT) ? bcount[t] : 0;
    part[t] = v;
    __syncthreads();
    for (int off = 1; off < 256; off <<= 1) {
        int u = (t >= off) ? part[t - off] : 0;
        __syncthreads();
        part[t] += u;
        __syncthreads();
    }
    const int incl = part[t];
    const int excl = incl - v;
    if (t < NBKT) { bOffs[t] = excl; cursor[t] = excl; }
    if (t == NBKT - 1) bOffs[NBKT] = incl;
}

// partition edges into bucket-contiguous ebuf with LDS staging (coalesced runs)
__global__ __launch_bounds__(256) void partition_kernel(
    const int* __restrict__ ei, int E, int* __restrict__ cursor,
    int2* __restrict__ ebuf)
{
    __shared__ int cnt[256], lofs[256], gbase[256], lcur[256];
    __shared__ int2 stage[EPB];
    __shared__ int tgt[EPB];
    const int t = threadIdx.x;
    const int base = blockIdx.x * EPB;
    const int n = min(EPB, E - base);

    int msrc[EPB / 256], mdst[EPB / 256];
    #pragma unroll
    for (int j = 0; j < EPB / 256; ++j) {
        const int idx = j * 256 + t;
        if (idx < n) { msrc[j] = ei[base + idx]; mdst[j] = ei[E + base + idx]; }
        else mdst[j] = -1;
    }
    cnt[t] = 0;
    __syncthreads();
    #pragma unroll
    for (int j = 0; j < EPB / 256; ++j)
        if (mdst[j] >= 0) atomicAdd(&cnt[mdst[j] >> 8], 1);
    __syncthreads();
    const int cv = cnt[t];
    lofs[t] = cv;
    __syncthreads();
    for (int off = 1; off < 256; off <<= 1) {
        int u = (t >= off) ? lofs[t - off] : 0;
        __syncthreads();
        lofs[t] += u;
        __syncthreads();
    }
    const int excl = lofs[t] - cv;
    gbase[t] = (cv > 0) ? atomicAdd(&cursor[t], cv) : 0;
    lcur[t] = 0;
    __syncthreads();
    lofs[t] = excl;
    __syncthreads();
    #pragma unroll
    for (int j = 0; j < EPB / 256; ++j) {
        if (mdst[j] >= 0) {
            const int b = mdst[j] >> 8;
            const int lp = atomicAdd(&lcur[b], 1);
            const int slot = lofs[b] + lp;
            stage[slot] = make_int2(msrc[j], mdst[j]);
            tgt[slot] = gbase[b] + lp;
        }
    }
    __syncthreads();
    for (int i = t; i < n; i += 256)
        ebuf[tgt[i]] = stage[i];
}

// per-bucket exact counting sort -> srcs (coalesced) + CSR offs
__global__ __launch_bounds__(256) void bucket_sort(
    const int2* __restrict__ ebuf, const int* __restrict__ bOffs,
    int* __restrict__ srcs, int* __restrict__ offs, int M)
{
    __shared__ int cnt[256], lofs[256], lcur[256];
    __shared__ int stage[STG];
    const int b = blockIdx.x, t = threadIdx.x;
    const int n0 = b << 8;
    const int lo = bOffs[b], hi = bOffs[b + 1];

    cnt[t] = 0;
    __syncthreads();
    for (int i = lo + t; i < hi; i += 256)
        atomicAdd(&cnt[ebuf[i].y - n0], 1);
    __syncthreads();
    const int cv = cnt[t];
    lofs[t] = cv;
    __syncthreads();
    for (int off = 1; off < 256; off <<= 1) {
        int u = (t >= off) ? lofs[t - off] : 0;
        __syncthreads();
        lofs[t] += u;
        __syncthreads();
    }
    const int excl = lofs[t] - cv;
    const int nn = min(256, M - n0);
    if (t < nn) offs[n0 + t] = lo + excl;
    if (b == NBKT - 1 && t == 0) offs[M] = hi;
    lcur[t] = 0;
    __syncthreads();
    lofs[t] = excl;
    __syncthreads();
    for (int i = lo + t; i < hi; i += 256) {
        const int2 p = ebuf[i];
        const int d = p.y - n0;
        const int lp = atomicAdd(&lcur[d], 1);
        const int slot = lofs[d] + lp;
        if (slot < STG) stage[slot] = p.x;
        else srcs[lo + slot] = p.x;       // overflow fallback (same target)
    }
    __syncthreads();
    const int n = hi - lo;
    for (int i = t; i < n && i < STG; i += 256)
        srcs[lo + i] = stage[i];
}

// ---- encoder: h0 = relu(x @ enc_w + enc_b), bf16 out. MFMA 16x16x32. ----
__global__ __launch_bounds__(256) void enc_mfma(
    const float* __restrict__ x, const unsigned short* __restrict__ encT,
    const float* __restrict__ enc_b, unsigned short* __restrict__ h0, int M)
{
    const int wave = threadIdx.x >> 6, lane = threadIdx.x & 63;
    const int rowBase = blockIdx.x * 64 + wave * 16;
    const int sl = lane & 15, kg = lane >> 4;
    const int row_a = rowBase + sl;

    f32x4 acc[8] = {};
    for (int ks = 0; ks < 8; ++ks) {
        const int k0 = ks * 32 + kg * 8;
        bf16x8 a = {};
        if (row_a < M) {
            const float* xp = x + (size_t)row_a * 256 + k0;
            float4 f0 = *(const float4*)xp;
            float4 f1 = *(const float4*)(xp + 4);
            a[0] = (short)f2b(f0.x); a[1] = (short)f2b(f0.y);
            a[2] = (short)f2b(f0.z); a[3] = (short)f2b(f0.w);
            a[4] = (short)f2b(f1.x); a[5] = (short)f2b(f1.y);
            a[6] = (short)f2b(f1.z); a[7] = (short)f2b(f1.w);
        }
        #pragma unroll
        for (int ct = 0; ct < 8; ++ct) {
            bf16x8 bfr = *(const bf16x8*)(encT + (size_t)(ct * 16 + sl) * 256 + k0);
            acc[ct] = __builtin_amdgcn_mfma_f32_16x16x32_bf16(a, bfr, acc[ct], 0, 0, 0);
        }
    }
    #pragma unroll
    for (int ct = 0; ct < 8; ++ct) {
        const int col = ct * 16 + sl;
        const float eb = enc_b[col];
        #pragma unroll
        for (int r = 0; r < 4; ++r) {
            const int row = rowBase + kg * 4 + r;
            if (row < M)
                h0[(size_t)row * 128 + col] = f2b(fmaxf(acc[ct][r] + eb, 0.f));
        }
    }
}

// ---- fused per-layer precompute: A -> outA [M][128]; B,L -> outBL [M][256] ----
__global__ __launch_bounds__(256) void fused3_mfma(
    const unsigned short* __restrict__ h,
    const unsigned short* __restrict__ AT, const unsigned short* __restrict__ BT,
    const unsigned short* __restrict__ LT, const float* __restrict__ linb,
    unsigned short* __restrict__ outA, unsigned short* __restrict__ outBL,
    int M)
{
    const int wave = threadIdx.x >> 6, lane = threadIdx.x & 63;
    const int rowBase = blockIdx.x * 64 + wave * 16;
    const int sl = lane & 15, kg = lane >> 4;
    const int row_a = rowBase + sl;

    bf16x8 afr[4];
    #pragma unroll
    for (int ks = 0; ks < 4; ++ks) {
        if (row_a < M)
            afr[ks] = *(const bf16x8*)(h + (size_t)row_a * 128 + ks * 32 + kg * 8);
        else
            afr[ks] = bf16x8{};
    }

    #pragma unroll
    for (int m = 0; m < 3; ++m) {
        const unsigned short* WT = (m == 0) ? AT : (m == 1) ? BT : LT;
        unsigned short* op  = (m == 0) ? outA : outBL;
        const int stride    = (m == 0) ? 128 : 256;
        const int coff      = (m == 2) ? 128 : 0;

        f32x4 acc[8] = {};
        #pragma unroll
        for (int ks = 0; ks < 4; ++ks) {
            const int k0 = ks * 32 + kg * 8;
            #pragma unroll
            for (int ct = 0; ct < 8; ++ct) {
                bf16x8 bfr = *(const bf16x8*)(WT + (size_t)(ct * 16 + sl) * 128 + k0);
                acc[ct] = __builtin_amdgcn_mfma_f32_16x16x32_bf16(afr[ks], bfr, acc[ct], 0, 0, 0);
            }
        }
        #pragma unroll
        for (int ct = 0; ct < 8; ++ct) {
            const int col = ct * 16 + sl;
            const float lb = (m == 2) ? linb[col] : 0.f;
            #pragma unroll
            for (int r = 0; r < 4; ++r) {
                const int row = rowBase + kg * 4 + r;
                if (row < M)
                    op[(size_t)row * stride + coff + col] = f2b(acc[ct][r] + lb);
            }
        }
    }
}

// ---- gather: one wave per dst node, one edge per 16-lane group.
// B and L interleaved in BL[M][256] (B at +0, L at +128).
template<bool CLS>
__global__ __launch_bounds__(256) void gather_bf16(
    const int* __restrict__ offs, const int* __restrict__ srcs,
    const unsigned short* __restrict__ Amat, const unsigned short* __restrict__ BL,
    const float* __restrict__ hid_b, const float* __restrict__ pw,
    const float* __restrict__ pb,
    unsigned short* __restrict__ outH,
    const float* __restrict__ cls_w, const float* __restrict__ cls_b,
    float* __restrict__ outC, int M)
{
    const int node = blockIdx.x * 4 + (threadIdx.x >> 6);
    if (node >= M) return;
    const int lane = threadIdx.x & 63;
    const int grp = lane >> 4;
    const int sl  = lane & 15;
    const int c8  = sl * 8;

    float a[8], w[8];
    {
        u16x8 av = *(const u16x8*)(Amat + (size_t)node * 128 + c8);
        float4 h0 = *(const float4*)(hid_b + c8);
        float4 h1 = *(const float4*)(hid_b + c8 + 4);
        a[0] = b2f(av[0]) + h0.x; a[1] = b2f(av[1]) + h0.y;
        a[2] = b2f(av[2]) + h0.z; a[3] = b2f(av[3]) + h0.w;
        a[4] = b2f(av[4]) + h1.x; a[5] = b2f(av[5]) + h1.y;
        a[6] = b2f(av[6]) + h1.z; a[7] = b2f(av[7]) + h1.w;
        float4 p0 = *(const float4*)(pw + c8);
        float4 p1 = *(const float4*)(pw + c8 + 4);
        w[0] = p0.x; w[1] = p0.y; w[2] = p0.z; w[3] = p0.w;
        w[4] = p1.x; w[5] = p1.y; w[6] = p1.z; w[7] = p1.w;
    }
    const float pb0 = pb[0];
    float acc[8] = {};

    const int start = offs[node], end = offs[node + 1];
    for (int idx = start + grp; idx < end; idx += 4) {
        const int s = srcs[idx];
        const unsigned short* row = BL + (size_t)s * 256 + c8;
        u16x8 bv = *(const u16x8*)row;
        u16x8 lv = *(const u16x8*)(row + 128);

        float part = 0.f;
        #pragma unroll
        for (int j = 0; j < 8; ++j)
            part += fmaxf(a[j] + b2f(bv[j]), 0.f) * w[j];
        part += __shfl_xor(part, 8);
        part += __shfl_xor(part, 4);
        part += __shfl_xor(part, 2);
        part += __shfl_xor(part, 1);

        const float pick = 1.f / (1.f + __expf(-(part + pb0)));
        #pragma unroll
        for (int j = 0; j < 8; ++j)
            acc[j] = fmaf(pick, b2f(lv[j]), acc[j]);
    }

    #pragma unroll
    for (int j = 0; j < 8; ++j) acc[j] += __shfl_xor(acc[j], 16);
    #pragma unroll
    for (int j = 0; j < 8; ++j) acc[j] += __shfl_xor(acc[j], 32);

    if (CLS) {
        float p0 = 0.f, p1 = 0.f;
        #pragma unroll
        for (int j = 0; j < 8; ++j) {
            p0 = fmaf(acc[j], cls_w[(c8 + j) * 2 + 0], p0);
            p1 = fmaf(acc[j], cls_w[(c8 + j) * 2 + 1], p1);
        }
        #pragma unroll
        for (int off = 8; off > 0; off >>= 1) {
            p0 += __shfl_xor(p0, off);
            p1 += __shfl_xor(p1, off);
        }
        if (lane == 0) {
            outC[(size_t)node * 2 + 0] = p0 + cls_b[0];
            outC[(size_t)node * 2 + 1] = p1 + cls_b[1];
        }
    } else {
        if (grp == 0) {
            u16x8 o;
            #pragma unroll
            for (int j = 0; j < 8; ++j)
                o[j] = f2b(fmaxf(acc[j], 0.f));     // relu before layer 2
            *(u16x8*)(outH + (size_t)node * 128 + c8) = o;
        }
    }
}

extern "C" void kernel_launch(void* const* d_in, const int* in_sizes, int n_in,
                              void* d_out, int out_size, void* d_ws, size_t ws_size,
                              hipStream_t stream)
{
    const float* x      = (const float*)d_in[0];
    const int*   ei     = (const int*)d_in[1];
    const float* enc_w  = (const float*)d_in[2];
    const float* enc_b  = (const float*)d_in[3];
    const float* lin1_w = (const float*)d_in[4];
    const float* lin1_b = (const float*)d_in[5];
    const float* p1a_w  = (const float*)d_in[6];
    const float* p1a_b  = (const float*)d_in[7];
    const float* p1b_w  = (const float*)d_in[8];
    const float* p1b_b  = (const float*)d_in[9];
    const float* lin2_w = (const float*)d_in[10];
    const float* lin2_b = (const float*)d_in[11];
    const float* p2a_w  = (const float*)d_in[12];
    const float* p2a_b  = (const float*)d_in[13];
    const float* p2b_w  = (const float*)d_in[14];
    const float* p2b_b  = (const float*)d_in[15];
    const float* cls_w  = (const float*)d_in[16];
    const float* cls_b  = (const float*)d_in[17];

    const int M = N_NODES_C;
    const int E = in_sizes[1] / 2;
    const size_t HS = (size_t)M * HIDDEN;          // ushorts per [M][128]

    unsigned short* Hb0 = (unsigned short*)d_ws;   // h0 -> A2
    unsigned short* HA  = Hb0 + HS;                // A1 -> relu(h1)
    unsigned short* HBL = HA + HS;                 // [M][256] B|L interleaved
    unsigned short* encT = HBL + 2 * HS;
    unsigned short* A1T = encT + 128 * 256;
    unsigned short* B1T = A1T + 128 * 128;
    unsigned short* L1T = B1T + 128 * 128;
    unsigned short* A2T = L1T + 128 * 128;
    unsigned short* B2T = A2T + 128 * 128;
    unsigned short* L2T = B2T + 128 * 128;
    int* offs   = (int*)(L2T + 128 * 128);         // M+1
    int* srcs   = offs + M + 1;                    // E
    int* bcount = srcs + E;                        // NBKT
    int* cursor = bcount + NBKT;                   // NBKT
    int* bOffs  = cursor + NBKT;                   // NBKT+1
    int2* ebuf  = (int2*)HBL;                      // overlay: dead before HBL write

    const int ggrid = (M + 63) / 64;
    const int ngrid = (M + 3) / 4;
    const int pgrid = (E + EPB - 1) / EPB;         // 196
    dim3 blk(256);

    // 1. weights bf16-transpose + zero bucket counters
    prep_kernel<<<65, blk, 0, stream>>>(enc_w, p1a_w, lin1_w, p2a_w, lin2_w,
                                        encT, A1T, B1T, L1T, A2T, B2T, L2T,
                                        bcount);
    // 2-5. CSR build via bucketed counting sort
    bucket_hist<<<pgrid, blk, 0, stream>>>(ei, E, bcount);
    bucket_scan<<<1, blk, 0, stream>>>(bcount, bOffs, cursor);
    partition_kernel<<<pgrid, blk, 0, stream>>>(ei, E, cursor, ebuf);
    bucket_sort<<<NBKT, blk, 0, stream>>>(ebuf, bOffs, srcs, offs, M);

    // 6. encoder
    enc_mfma<<<ggrid, blk, 0, stream>>>(x, encT, enc_b, Hb0, M);

    // 7-8. layer 1
    fused3_mfma<<<ggrid, blk, 0, stream>>>(Hb0, A1T, B1T, L1T, lin1_b,
                                           HA, HBL, M);
    gather_bf16<false><<<ngrid, blk, 0, stream>>>(offs, srcs, HA, HBL,
                                                  p1a_b, p1b_w, p1b_b,
                                                  HA, nullptr, nullptr, nullptr, M);

    // 9-10. layer 2 (+ fused classifier)
    fused3_mfma<<<ggrid, blk, 0, stream>>>(HA, A2T, B2T, L2T, lin2_b,
                                           Hb0, HBL, M);
    gather_bf16<true><<<ngrid, blk, 0, stream>>>(offs, srcs, Hb0, HBL,
                                                 p2a_b, p2b_w, p2b_b,
                                                 nullptr, cls_w, cls_b,
                                                 (float*)d_out, M);
}